// Round 9
// baseline (1767.896 us; speedup 1.0000x reference)
//
#include <hip/hip_runtime.h>
#include <math.h>

// CepstrumToImpulseResponse: per row r (131072 rows):
//   h[0] = exp(c[0]);  h[n] = (1/n) * sum_{k=1}^{min(n,255)} (k*c_k) * h[n-k]
//
// R9 = R8 + occupancy push (safe this time) + setprio.
//  - R8 measured VGPR_Count=52; __launch_bounds__(256,8) gives the register
//    allocator a 64-reg budget it ALREADY fits (R6's spill was a ~110-reg
//    structure under the same cap). LDS 18.9KB/block allows exactly 8
//    blocks/CU -> 8 waves/SIMD (vs 4), covering the serial-fixup + DPP-reduce
//    latency chains that held issue efficiency at ~74%.
//  - s_setprio(1) around the fdot2 cluster: independent waves (no barriers
//    in the main loop) = the measured-positive setprio case.
// Spill tripwire: FETCH_SIZE >> 66MB means the cap spilled -> revert.
//
// Core structure (R8): 8 rows/wave (8 lanes/row), J=8 outputs/iter, per-row
// 256-half f16 ring, v_dot2_f32_f16 MACs vs 38 packed f16x2 coeff pairs
// (1 MAC/lane/cyc measured -- same as f32 FMA rate; f16 wins via halved LDS
// traffic + register footprint, not MAC rate), DPP 8-lane reduce, f32 serial
// fixup k=1..7, register forwarding of newest 8 h's (lane-7 substitution),
// 1-iter window prefetch, register output staging, coalesced 256B/row flush.

constexpr int ROWS_PER_BLOCK = 32;   // 4 waves x 8 rows
constexpr int THREADS = 256;
constexpr int CLEN = 256;            // c row length (M+1)
constexpr int NOUT = 512;            // IR length
constexpr int RHALVES = 264;         // 256-half ring (512B) + 8 pad halves
constexpr int NITER = NOUT / 8;      // 8 outputs per iteration

typedef float f4 __attribute__((ext_vector_type(4)));
typedef _Float16 half2_t __attribute__((ext_vector_type(2)));

// Sum v across each aligned 8-lane group; every lane gets the group total.
// quad_perm(1,0,3,2)=0xB1, quad_perm(2,3,0,1)=0x4E, row_half_mirror=0x141
__device__ __forceinline__ float row8_sum(float v) {
  int x;
  x = __builtin_amdgcn_update_dpp(0, __float_as_int(v), 0xB1, 0xF, 0xF, true);
  v += __int_as_float(x);
  x = __builtin_amdgcn_update_dpp(0, __float_as_int(v), 0x4E, 0xF, 0xF, true);
  v += __int_as_float(x);
  x = __builtin_amdgcn_update_dpp(0, __float_as_int(v), 0x141, 0xF, 0xF, true);
  v += __int_as_float(x);
  return v;
}

__global__ __launch_bounds__(THREADS, 8) void cep2ir_kernel(
    const float* __restrict__ c, float* __restrict__ out, int nrows) {
  __shared__ ushort HF[ROWS_PER_BLOCK][RHALVES];   // f16 h-history rings
  __shared__ float INV[NOUT];

  const int tid = threadIdx.x;
  const int lane = tid & 63;
  const int wid = tid >> 6;
  const int s = lane & 7;                  // sublane within 8-lane row group
  const int rl = (wid << 3) | (lane >> 3); // row within block, 0..31

  for (int i = tid; i < NOUT; i += THREADS)
    INV[i] = (i == 0) ? 0.0f : 1.0f / (float)i;
  // Zero all rings (as uints; RHALVES is even -> rows stay uint-aligned).
  uint* hz = (uint*)&HF[0][0];
  for (int i = tid; i < ROWS_PER_BLOCK * RHALVES / 2; i += THREADS)
    hz[i] = 0u;
  __syncthreads();  // uniform: all threads reach this before divergence

  const long long row = (long long)blockIdx.x * ROWS_PER_BLOCK + rl;
  if (row < nrows) {
    const float* __restrict__ crow = c + row * (long long)CLEN;

    // Lane s owns window positions pos = 32s + eps, eps = 0..31
    // (pos 0 = oldest h[n-256], pos 255 = newest h[n-1]).
    // Coef index k = 256 + j - pos = K + j - eps, K = 256 - 32s.
    // R(u) = kc(K+7-u); packed pairs P[u] = (R(u), R(u+1)), u = 0..37.
    // For window pair p (eps = 2p,2p+1), output j: dot2 with P[2p + 7-j].
    const int K = 256 - 32 * s;
    half2_t P[38];
#pragma unroll
    for (int u = 0; u < 38; ++u) {
      const int kx = K + 7 - u;
      const int ky = kx - 1;
      const float px = (kx >= 1 && kx <= 255) ? (float)kx * crow[kx] : 0.0f;
      const float py = (ky >= 1 && ky <= 255) ? (float)ky * crow[ky] : 0.0f;
      P[u] = __builtin_bit_cast(half2_t, __builtin_amdgcn_cvt_pkrtz(px, py));
    }

    const float kc1 = crow[1];
    const float kc2 = 2.0f * crow[2];
    const float kc3 = 3.0f * crow[3];
    const float kc4 = 4.0f * crow[4];
    const float kc5 = 5.0f * crow[5];
    const float kc6 = 6.0f * crow[6];
    const float kc7 = 7.0f * crow[7];
    const float h0val = expf(crow[0]);
    const bool is7 = (s == 7);

    char* __restrict__ Hb = (char*)&HF[rl][0];
    int wo = (-16) & 508;                    // ring write offset (bytes)
    float* __restrict__ gp = out + row * (long long)NOUT + 8 * s;

    // Prime: window chunk reads for it=0 (all-zero region of the ring).
    // At iter it, chunk cix byte offset = (64s + 16*cix + 16*it) & 508.
    uint4 cw0 = *(const uint4*)(Hb + ((64 * s + 0)  & 508));
    uint4 cw1 = *(const uint4*)(Hb + ((64 * s + 16) & 508));
    uint4 cw2 = *(const uint4*)(Hb + ((64 * s + 32) & 508));
    uint4 cw3 = *(const uint4*)(Hb + ((64 * s + 48) & 508));
    // Rolling offsets for the NEXT prefetch (it=1).
    int ro0 = (64 * s + 0  + 16) & 508;
    int ro1 = (64 * s + 16 + 16) & 508;
    int ro2 = (64 * s + 32 + 16) & 508;
    int ro3 = (64 * s + 48 + 16) & 508;

    uint4 qn; qn.x = 0u; qn.y = 0u; qn.z = 0u; qn.w = 0u;  // forwarded h's

    // Register output staging: lane s keeps the y's of the iteration with
    // (it&7)==s, then writes its own 32B slice at flush (coalesced).
    float ys0 = 0.f, ys1 = 0.f, ys2 = 0.f, ys3 = 0.f;
    float ys4 = 0.f, ys5 = 0.f, ys6 = 0.f, ys7 = 0.f;

#pragma unroll 2
    for (int it = 0; it < NITER; ++it) {
      // ---- Prefetch window chunks for it+1 (any ordering vs this iter's
      // ds_write is correct: lane7-chunk3 is overridden by qn next iter).
      const uint4 pw0 = *(const uint4*)(Hb + ro0);
      const uint4 pw1 = *(const uint4*)(Hb + ro1);
      const uint4 pw2 = *(const uint4*)(Hb + ro2);
      const uint4 pw3 = *(const uint4*)(Hb + ro3);
      ro0 = (ro0 + 16) & 508; ro1 = (ro1 + 16) & 508;
      ro2 = (ro2 + 16) & 508; ro3 = (ro3 + 16) & 508;

      // ---- Lane-7 substitution: newest 8 h's come from registers.
      uint4 w3u;
      w3u.x = is7 ? qn.x : cw3.x;
      w3u.y = is7 ? qn.y : cw3.y;
      w3u.z = is7 ? qn.z : cw3.z;
      w3u.w = is7 ? qn.w : cw3.w;

      float A0 = 0.f, A1 = 0.f, A2 = 0.f, A3 = 0.f;
      float A4 = 0.f, A5 = 0.f, A6 = 0.f, A7 = 0.f;

      __builtin_amdgcn_s_setprio(1);
      // Pair p at ubase = 2p: A_j += dot2(h2, P[ubase + 7 - j]).
#define DOTQ(wu, ub)                                                   \
      { const half2_t q = __builtin_bit_cast(half2_t, (wu));           \
        A0 = __builtin_amdgcn_fdot2(q, P[(ub) + 7], A0, false);        \
        A1 = __builtin_amdgcn_fdot2(q, P[(ub) + 6], A1, false);        \
        A2 = __builtin_amdgcn_fdot2(q, P[(ub) + 5], A2, false);        \
        A3 = __builtin_amdgcn_fdot2(q, P[(ub) + 4], A3, false);        \
        A4 = __builtin_amdgcn_fdot2(q, P[(ub) + 3], A4, false);        \
        A5 = __builtin_amdgcn_fdot2(q, P[(ub) + 2], A5, false);        \
        A6 = __builtin_amdgcn_fdot2(q, P[(ub) + 1], A6, false);        \
        A7 = __builtin_amdgcn_fdot2(q, P[(ub) + 0], A7, false); }
      DOTQ(cw0.x, 0)  DOTQ(cw0.y, 2)  DOTQ(cw0.z, 4)  DOTQ(cw0.w, 6)
      DOTQ(cw1.x, 8)  DOTQ(cw1.y, 10) DOTQ(cw1.z, 12) DOTQ(cw1.w, 14)
      DOTQ(cw2.x, 16) DOTQ(cw2.y, 18) DOTQ(cw2.z, 20) DOTQ(cw2.w, 22)
      DOTQ(w3u.x, 24) DOTQ(w3u.y, 26) DOTQ(w3u.z, 28) DOTQ(w3u.w, 30)
#undef DOTQ
      __builtin_amdgcn_s_setprio(0);

      // 8-lane row sums (broadcast to all lanes of the row).
      const float a0 = row8_sum(A0);
      const float a1 = row8_sum(A1);
      const float a2 = row8_sum(A2);
      const float a3 = row8_sum(A3);
      const float a4 = row8_sum(A4);
      const float a5 = row8_sum(A5);
      const float a6 = row8_sum(A6);
      const float a7 = row8_sum(A7);

      const int n = it * 8;
      const f4 ivA = *(const f4*)(&INV[n]);
      const f4 ivB = *(const f4*)(&INV[n + 4]);

      // Serial fixup (f32): intra-block terms k=1..7 on the new h's.
      const float y0 = (it == 0) ? h0val : a0 * ivA.x;
      const float y1 = fmaf(kc1, y0, a1) * ivA.y;
      const float y2 = fmaf(kc1, y1, fmaf(kc2, y0, a2)) * ivA.z;
      const float y3 = fmaf(kc1, y2, fmaf(kc2, y1, fmaf(kc3, y0, a3))) * ivA.w;
      const float y4 = fmaf(kc1, y3, fmaf(kc2, y2, fmaf(kc3, y1,
                          fmaf(kc4, y0, a4)))) * ivB.x;
      const float y5 = fmaf(kc1, y4, fmaf(kc2, y3, fmaf(kc3, y2,
                          fmaf(kc4, y1, fmaf(kc5, y0, a5))))) * ivB.y;
      const float y6 = fmaf(kc1, y5, fmaf(kc2, y4, fmaf(kc3, y3,
                          fmaf(kc4, y2, fmaf(kc5, y1,
                          fmaf(kc6, y0, a6)))))) * ivB.z;
      const float y7 = fmaf(kc1, y6, fmaf(kc2, y5, fmaf(kc3, y4,
                          fmaf(kc4, y3, fmaf(kc5, y2, fmaf(kc6, y1,
                          fmaf(kc7, y0, a7)))))))  * ivB.w;

      // Pack new h's (ALL lanes -- needed for forwarding); lane 0 writes the
      // ring for consumers >= 2 iterations out.
      uint4 wq;
      wq.x = __builtin_bit_cast(uint, __builtin_amdgcn_cvt_pkrtz(y0, y1));
      wq.y = __builtin_bit_cast(uint, __builtin_amdgcn_cvt_pkrtz(y2, y3));
      wq.z = __builtin_bit_cast(uint, __builtin_amdgcn_cvt_pkrtz(y4, y5));
      wq.w = __builtin_bit_cast(uint, __builtin_amdgcn_cvt_pkrtz(y6, y7));
      qn = wq;
      wo = (wo + 16) & 508;
      if (s == 0) {
        *(uint4*)(Hb + wo) = wq;
      }

      // Register staging: lane s keeps this iteration's y's iff (it&7)==s.
      if ((it & 7) == s) {
        ys0 = y0; ys1 = y1; ys2 = y2; ys3 = y3;
        ys4 = y4; ys5 = y5; ys6 = y6; ys7 = y7;
      }

      // Every 8 iters: flush 64 finished f32 outputs, coalesced 256B/row.
      if ((it & 7) == 7) {
        f4 v0; v0.x = ys0; v0.y = ys1; v0.z = ys2; v0.w = ys3;
        f4 v1; v1.x = ys4; v1.y = ys5; v1.z = ys6; v1.w = ys7;
        *(f4*)(gp) = v0;
        *(f4*)(gp + 4) = v1;
        gp += 64;
      }

      // Rotate prefetched window into place.
      cw0 = pw0; cw1 = pw1; cw2 = pw2; cw3 = pw3;
    }
  }
}

extern "C" void kernel_launch(void* const* d_in, const int* in_sizes, int n_in,
                              void* d_out, int out_size, void* d_ws, size_t ws_size,
                              hipStream_t stream) {
  const float* c = (const float*)d_in[0];
  float* out = (float*)d_out;
  const int nrows = in_sizes[0] / CLEN;
  const int nblocks = (nrows + ROWS_PER_BLOCK - 1) / ROWS_PER_BLOCK;
  hipLaunchKernelGGL(cep2ir_kernel, dim3(nblocks), dim3(THREADS), 0, stream,
                     c, out, nrows);
}

// Round 11
// 376.455 us; speedup vs baseline: 4.6962x; 4.6962x over previous
//
#include <hip/hip_runtime.h>
#include <math.h>

// CepstrumToImpulseResponse: per row r (131072 rows):
//   h[0] = exp(c[0]);  h[n] = (1/n) * sum_{k=1}^{min(n,255)} (k*c_k) * h[n-k]
//
// R11 = R8 + HALF-WINDOW PHASE 1 (the spill-free version of R7's idea).
//  - Phase 1 (it 0..15, outputs n <= 127): a 128-wide window covers all
//    needed history (h[0..n-1] subset of window for n <= 127). 16 pos/lane,
//    2 chunk reads (32B lane stride -> 2-way bank aliasing = free), 22
//    coefficient pairs with NO range guards (k in [2,135] for all lanes).
//    Saves 64 of 128 dots/iter for 16 iters = 12.5% of all dots.
//  - Phase 2 (it 16..63): the R8 body verbatim (prefetch, lane-7 register
//    forwarding, register output staging).
//  - Spill fix vs R7: P1 lives in its own scope and P2[38] is loaded AFTER
//    phase 1 completes (crow re-read is L1-hot) -> coefficient sets are
//    never simultaneously live.
//  - R10's wave-uniform dead-chunk skip was WRONG (liveness is per-lane in
//    the lane-major layout); this phase split is the correct uniform cut.
// Launch bounds pinned at (256,4): (256,8) twice produced VGPR=32 + scratch
// spill (R6: +613MB, R9: +6.3GB FETCH). No setprio (R9 artifact).
//
// Core structure (R8): 8 rows/wave (8 lanes/row), J=8 outputs/iter, per-row
// 256-half f16 ring, v_dot2_f32_f16 MACs (1 MAC/lane/cyc -- f16 wins via
// halved LDS traffic + packed registers, not MAC rate), DPP 8-lane reduce,
// f32 serial fixup k=1..7, coalesced 256B/row flush every 8 iters.

constexpr int ROWS_PER_BLOCK = 32;   // 4 waves x 8 rows
constexpr int THREADS = 256;
constexpr int CLEN = 256;            // c row length (M+1)
constexpr int NOUT = 512;            // IR length
constexpr int RHALVES = 264;         // 256-half ring (512B) + 8 pad halves

typedef float f4 __attribute__((ext_vector_type(4)));
typedef _Float16 half2_t __attribute__((ext_vector_type(2)));

// Sum v across each aligned 8-lane group; every lane gets the group total.
// quad_perm(1,0,3,2)=0xB1, quad_perm(2,3,0,1)=0x4E, row_half_mirror=0x141
__device__ __forceinline__ float row8_sum(float v) {
  int x;
  x = __builtin_amdgcn_update_dpp(0, __float_as_int(v), 0xB1, 0xF, 0xF, true);
  v += __int_as_float(x);
  x = __builtin_amdgcn_update_dpp(0, __float_as_int(v), 0x4E, 0xF, 0xF, true);
  v += __int_as_float(x);
  x = __builtin_amdgcn_update_dpp(0, __float_as_int(v), 0x141, 0xF, 0xF, true);
  v += __int_as_float(x);
  return v;
}

// One window pair (2 f16 in wu) against 8 outputs; output j uses P[ub+7-j].
#define DOTQ(P, wu, ub)                                                \
      { const half2_t q = __builtin_bit_cast(half2_t, (wu));           \
        A0 = __builtin_amdgcn_fdot2(q, P[(ub) + 7], A0, false);        \
        A1 = __builtin_amdgcn_fdot2(q, P[(ub) + 6], A1, false);        \
        A2 = __builtin_amdgcn_fdot2(q, P[(ub) + 5], A2, false);        \
        A3 = __builtin_amdgcn_fdot2(q, P[(ub) + 4], A3, false);        \
        A4 = __builtin_amdgcn_fdot2(q, P[(ub) + 3], A4, false);        \
        A5 = __builtin_amdgcn_fdot2(q, P[(ub) + 2], A5, false);        \
        A6 = __builtin_amdgcn_fdot2(q, P[(ub) + 1], A6, false);        \
        A7 = __builtin_amdgcn_fdot2(q, P[(ub) + 0], A7, false); }

// Reduce + fixup + ring write + staging/flush (shared by both phases).
#define ITER_TAIL(Y0EXPR)                                                \
      const float a0 = row8_sum(A0);                                     \
      const float a1 = row8_sum(A1);                                     \
      const float a2 = row8_sum(A2);                                     \
      const float a3 = row8_sum(A3);                                     \
      const float a4 = row8_sum(A4);                                     \
      const float a5 = row8_sum(A5);                                     \
      const float a6 = row8_sum(A6);                                     \
      const float a7 = row8_sum(A7);                                     \
      const int n = it * 8;                                              \
      const f4 ivA = *(const f4*)(&INV[n]);                              \
      const f4 ivB = *(const f4*)(&INV[n + 4]);                          \
      const float y0 = (Y0EXPR);                                         \
      const float y1 = fmaf(kc1, y0, a1) * ivA.y;                        \
      const float y2 = fmaf(kc1, y1, fmaf(kc2, y0, a2)) * ivA.z;         \
      const float y3 = fmaf(kc1, y2, fmaf(kc2, y1,                       \
                          fmaf(kc3, y0, a3))) * ivA.w;                   \
      const float y4 = fmaf(kc1, y3, fmaf(kc2, y2, fmaf(kc3, y1,         \
                          fmaf(kc4, y0, a4)))) * ivB.x;                  \
      const float y5 = fmaf(kc1, y4, fmaf(kc2, y3, fmaf(kc3, y2,         \
                          fmaf(kc4, y1, fmaf(kc5, y0, a5))))) * ivB.y;   \
      const float y6 = fmaf(kc1, y5, fmaf(kc2, y4, fmaf(kc3, y3,         \
                          fmaf(kc4, y2, fmaf(kc5, y1,                    \
                          fmaf(kc6, y0, a6)))))) * ivB.z;                \
      const float y7 = fmaf(kc1, y6, fmaf(kc2, y5, fmaf(kc3, y4,         \
                          fmaf(kc4, y3, fmaf(kc5, y2, fmaf(kc6, y1,      \
                          fmaf(kc7, y0, a7)))))))  * ivB.w;              \
      uint4 wq;                                                          \
      wq.x = __builtin_bit_cast(uint, __builtin_amdgcn_cvt_pkrtz(y0, y1)); \
      wq.y = __builtin_bit_cast(uint, __builtin_amdgcn_cvt_pkrtz(y2, y3)); \
      wq.z = __builtin_bit_cast(uint, __builtin_amdgcn_cvt_pkrtz(y4, y5)); \
      wq.w = __builtin_bit_cast(uint, __builtin_amdgcn_cvt_pkrtz(y6, y7)); \
      qn = wq;                                                           \
      wo = (wo + 16) & 508;                                              \
      if (s == 0) {                                                      \
        *(uint4*)(Hb + wo) = wq;   /* same-wave DS ops are in-order */   \
      }                                                                  \
      if ((it & 7) == s) {                                               \
        ys0 = y0; ys1 = y1; ys2 = y2; ys3 = y3;                          \
        ys4 = y4; ys5 = y5; ys6 = y6; ys7 = y7;                          \
      }                                                                  \
      if ((it & 7) == 7) {                                               \
        f4 v0; v0.x = ys0; v0.y = ys1; v0.z = ys2; v0.w = ys3;           \
        f4 v1; v1.x = ys4; v1.y = ys5; v1.z = ys6; v1.w = ys7;           \
        *(f4*)(gp) = v0;                                                 \
        *(f4*)(gp + 4) = v1;                                             \
        gp += 64;                                                        \
      }

__global__ __launch_bounds__(THREADS, 4) void cep2ir_kernel(
    const float* __restrict__ c, float* __restrict__ out, int nrows) {
  __shared__ ushort HF[ROWS_PER_BLOCK][RHALVES];   // f16 h-history rings
  __shared__ float INV[NOUT];

  const int tid = threadIdx.x;
  const int lane = tid & 63;
  const int wid = tid >> 6;
  const int s = lane & 7;                  // sublane within 8-lane row group
  const int rl = (wid << 3) | (lane >> 3); // row within block, 0..31

  for (int i = tid; i < NOUT; i += THREADS)
    INV[i] = (i == 0) ? 0.0f : 1.0f / (float)i;
  // Zero all rings (as uints; RHALVES is even -> rows stay uint-aligned).
  uint* hz = (uint*)&HF[0][0];
  for (int i = tid; i < ROWS_PER_BLOCK * RHALVES / 2; i += THREADS)
    hz[i] = 0u;
  __syncthreads();  // uniform: all threads reach this before divergence

  const long long row = (long long)blockIdx.x * ROWS_PER_BLOCK + rl;
  if (row < nrows) {
    const float* __restrict__ crow = c + row * (long long)CLEN;

    const float kc1 = crow[1];
    const float kc2 = 2.0f * crow[2];
    const float kc3 = 3.0f * crow[3];
    const float kc4 = 4.0f * crow[4];
    const float kc5 = 5.0f * crow[5];
    const float kc6 = 6.0f * crow[6];
    const float kc7 = 7.0f * crow[7];
    const float h0val = expf(crow[0]);
    const bool is7 = (s == 7);

    char* __restrict__ Hb = (char*)&HF[rl][0];
    int wo = (-16) & 508;                    // ring write offset (bytes)
    float* __restrict__ gp = out + row * (long long)NOUT + 8 * s;

    uint4 qn; qn.x = 0u; qn.y = 0u; qn.z = 0u; qn.w = 0u;  // forwarded h's

    // Register output staging: lane s keeps the y's of the iteration with
    // (it&7)==s, then writes its own 32B slice at flush (coalesced).
    float ys0 = 0.f, ys1 = 0.f, ys2 = 0.f, ys3 = 0.f;
    float ys4 = 0.f, ys5 = 0.f, ys6 = 0.f, ys7 = 0.f;

    // ------------- Phase 1: it = 0..15, 128-wide window -------------
    // Lane s owns window pos p = 16s + eps, eps = 0..15 (p 0 = h[n-128],
    // p 127 = h[n-1]). Coef k = n + j - m, m = 8it - 128 + p
    //   -> k = K1 + j - eps, K1 = 128 - 16s.
    // P1[u] = (kc(K1+7-u), kc(K1+6-u)), u = 0..21; window pair pp
    // (eps = 2pp, 2pp+1) for output j uses P1[2pp + 7 - j].
    // k range over all lanes: [2, 135] -> no clamping needed.
    // Ring byte of p: (16it + 256 + 32s + 2eps) mod 512. 32B lane stride.
    {
      const int K1 = 128 - 16 * s;
      half2_t P1[22];
#pragma unroll
      for (int u = 0; u < 22; ++u) {
        const int kx = K1 + 7 - u;          // in [2,135]
        P1[u] = __builtin_bit_cast(half2_t, __builtin_amdgcn_cvt_pkrtz(
                    (float)kx * crow[kx], (float)(kx - 1) * crow[kx - 1]));
      }

#pragma unroll 2
      for (int it = 0; it < 16; ++it) {
        const int b0 = (16 * it + 256 + 32 * s) & 508;
        const int b1 = (b0 + 16) & 508;
        const uint4 u0 = *(const uint4*)(Hb + b0);   // eps 0..7
        const uint4 u1r = *(const uint4*)(Hb + b1);  // eps 8..15
        // Newest 8 h's live at (s=7, eps 8..15): forward from registers.
        uint4 u1;
        u1.x = is7 ? qn.x : u1r.x;
        u1.y = is7 ? qn.y : u1r.y;
        u1.z = is7 ? qn.z : u1r.z;
        u1.w = is7 ? qn.w : u1r.w;

        float A0 = 0.f, A1 = 0.f, A2 = 0.f, A3 = 0.f;
        float A4 = 0.f, A5 = 0.f, A6 = 0.f, A7 = 0.f;
        DOTQ(P1, u0.x, 0)  DOTQ(P1, u0.y, 2)
        DOTQ(P1, u0.z, 4)  DOTQ(P1, u0.w, 6)
        DOTQ(P1, u1.x, 8)  DOTQ(P1, u1.y, 10)
        DOTQ(P1, u1.z, 12) DOTQ(P1, u1.w, 14)

        ITER_TAIL((it == 0) ? h0val : a0 * ivA.x)
      }
    }

    // ------------- Phase 2: it = 16..63, 256-wide window -------------
    // Lane s owns pos = 32s + eps, eps = 0..31. K = 256 - 32s.
    // P[u] = (kc(K+7-u), kc(K+6-u)), u = 0..37 (clamped outside [1,255]).
    // Loaded AFTER phase 1 so the two coefficient sets are never both live.
    {
      const int K = 256 - 32 * s;
      half2_t P[38];
#pragma unroll
      for (int u = 0; u < 38; ++u) {
        const int kx = K + 7 - u;
        const int ky = kx - 1;
        const float px = (kx >= 1 && kx <= 255) ? (float)kx * crow[kx] : 0.0f;
        const float py = (ky >= 1 && ky <= 255) ? (float)ky * crow[ky] : 0.0f;
        P[u] = __builtin_bit_cast(half2_t, __builtin_amdgcn_cvt_pkrtz(px, py));
      }

      // Prime window chunks for it=16; rolling offsets for the it=17 fetch.
      // Chunk cix byte offset at iter it: (64s + 16cix + 16it) & 508.
      uint4 cw0 = *(const uint4*)(Hb + ((64 * s + 0  + 256) & 508));
      uint4 cw1 = *(const uint4*)(Hb + ((64 * s + 16 + 256) & 508));
      uint4 cw2 = *(const uint4*)(Hb + ((64 * s + 32 + 256) & 508));
      uint4 cw3 = *(const uint4*)(Hb + ((64 * s + 48 + 256) & 508));
      int ro0 = (64 * s + 0  + 272) & 508;
      int ro1 = (64 * s + 16 + 272) & 508;
      int ro2 = (64 * s + 32 + 272) & 508;
      int ro3 = (64 * s + 48 + 272) & 508;

#pragma unroll 2
      for (int it = 16; it < 64; ++it) {
        // Prefetch window chunks for it+1 (ordering vs this iter's ds_write
        // is safe: lane7-chunk3 is overridden by qn next iter).
        const uint4 pw0 = *(const uint4*)(Hb + ro0);
        const uint4 pw1 = *(const uint4*)(Hb + ro1);
        const uint4 pw2 = *(const uint4*)(Hb + ro2);
        const uint4 pw3 = *(const uint4*)(Hb + ro3);
        ro0 = (ro0 + 16) & 508; ro1 = (ro1 + 16) & 508;
        ro2 = (ro2 + 16) & 508; ro3 = (ro3 + 16) & 508;

        // Lane-7 substitution: newest 8 h's come from registers.
        uint4 w3u;
        w3u.x = is7 ? qn.x : cw3.x;
        w3u.y = is7 ? qn.y : cw3.y;
        w3u.z = is7 ? qn.z : cw3.z;
        w3u.w = is7 ? qn.w : cw3.w;

        float A0 = 0.f, A1 = 0.f, A2 = 0.f, A3 = 0.f;
        float A4 = 0.f, A5 = 0.f, A6 = 0.f, A7 = 0.f;
        DOTQ(P, cw0.x, 0)  DOTQ(P, cw0.y, 2)
        DOTQ(P, cw0.z, 4)  DOTQ(P, cw0.w, 6)
        DOTQ(P, cw1.x, 8)  DOTQ(P, cw1.y, 10)
        DOTQ(P, cw1.z, 12) DOTQ(P, cw1.w, 14)
        DOTQ(P, cw2.x, 16) DOTQ(P, cw2.y, 18)
        DOTQ(P, cw2.z, 20) DOTQ(P, cw2.w, 22)
        DOTQ(P, w3u.x, 24) DOTQ(P, w3u.y, 26)
        DOTQ(P, w3u.z, 28) DOTQ(P, w3u.w, 30)

        ITER_TAIL(a0 * ivA.x)

        // Rotate prefetched window into place.
        cw0 = pw0; cw1 = pw1; cw2 = pw2; cw3 = pw3;
      }
    }
  }
}

extern "C" void kernel_launch(void* const* d_in, const int* in_sizes, int n_in,
                              void* d_out, int out_size, void* d_ws, size_t ws_size,
                              hipStream_t stream) {
  const float* c = (const float*)d_in[0];
  float* out = (float*)d_out;
  const int nrows = in_sizes[0] / CLEN;
  const int nblocks = (nrows + ROWS_PER_BLOCK - 1) / ROWS_PER_BLOCK;
  hipLaunchKernelGGL(cep2ir_kernel, dim3(nblocks), dim3(THREADS), 0, stream,
                     c, out, nrows);
}